// Round 4
// baseline (89.193 us; speedup 1.0000x reference)
//
#include <hip/hip_runtime.h>
#include <stdint.h>

#define NIN 1024
#define NMID 256
#define NOUT 64
#define BM 128
#define BK 64

typedef __attribute__((ext_vector_type(8))) short bf16x8;
typedef __attribute__((ext_vector_type(4))) float fx4;
typedef __attribute__((ext_vector_type(16))) float f32x16;
typedef __attribute__((ext_vector_type(4))) uint32_t u32x4;

#define XS_TILE 32768   // [128 rows][256B fp32], XOR-16 swizzled 16B chunks
#define LDS_SZ  65536   // x dbuf 2x32K; h[128][512B] (64K) overlays after loop

union FragU { bf16x8 v; uint32_t u[4]; };

static __device__ __forceinline__ uint32_t cvtpk(float lo, float hi) {
  uint32_t r;
  asm("v_cvt_pk_bf16_f32 %0, %1, %2" : "=v"(r) : "v"(lo), "v"(hi));
  return r;
}
static __device__ __forceinline__ void gload16(const void* g, void* l) {
  __builtin_amdgcn_global_load_lds(
      (const __attribute__((address_space(1))) uint32_t*)g,
      (__attribute__((address_space(3))) uint32_t*)l, 16, 0, 0);
}

// ---- kernel 1: W1 -> MFMA-fragment-ready bf16 layout, W2 -> bf16 rowmajor ----
// w1f element addr = (c*4096 + kb*32 + r)*8 + e  where n = c*32+r, k = kb*8+e.
// A wave's B-fragment load (c fixed, kb fixed, r = lane&31, e 0..7, lh in kb)
// is then 64 lanes x contiguous 16B = fully coalesced 1KB.
__global__ __launch_bounds__(256) void cvt_weights(
    const float* __restrict__ W1, const float* __restrict__ W2,
    unsigned short* __restrict__ w1f, unsigned short* __restrict__ w2b) {
  int gid = blockIdx.x * 256 + threadIdx.x;
  if (gid < 32768) {                      // 8 c * 128 kb * 32 r
    int r = gid & 31;
    int kb = (gid >> 5) & 127;
    int c = gid >> 12;
    const float* s = W1 + (size_t)(c * 32 + r) * NIN + kb * 8;
    fx4 v0 = *(const fx4*)s;
    fx4 v1 = *(const fx4*)(s + 4);
    u32x4 o = {cvtpk(v0.x, v0.y), cvtpk(v0.z, v0.w),
               cvtpk(v1.x, v1.y), cvtpk(v1.z, v1.w)};
    *(u32x4*)(w1f + (size_t)gid * 8) = o;
  } else {
    int e2 = (gid - 32768) << 2;
    if (e2 < NOUT * NMID) {
      fx4 v = *(const fx4*)(W2 + e2);
      uint2 p; p.x = cvtpk(v.x, v.y); p.y = cvtpk(v.z, v.w);
      *(uint2*)(w2b + e2) = p;
    }
  }
}

// ---- kernel 2: fused MLP. 512 thr (8 waves: wm 0..1 x wn 0..3), BM=128 ----
// x: fp32 global -> LDS via global_load_lds (linear dest, pre-swizzled src),
//    double-buffered; converted to bf16 at fragment read (cvt_pk).
// W1: fragment-ready bf16 straight from L2 (no LDS).
__global__ __launch_bounds__(512, 4) void livenet_main(
    const float* __restrict__ x,
    const unsigned short* __restrict__ w1f,
    const float* __restrict__ b1,
    const unsigned short* __restrict__ w2b,
    const float* __restrict__ b2,
    float* __restrict__ y) {

  extern __shared__ __align__(16) char smem[];

  const int tid = threadIdx.x;
  const int lane = tid & 63;
  const int w = tid >> 6;
  const int wm = w >> 2;       // row half (0..1)
  const int wn = w & 3;        // col quarter (0..3)
  const int l31 = lane & 31;
  const int l15 = lane & 15;
  const int lh = lane >> 5;    // k-half within fragment
  const int row0 = blockIdx.x * BM;

  // x staging: 4 chunks/thread, linear LDS dest, inverse-swizzled global src
  uint32_t xsrc[4], xdst[4];
#pragma unroll
  for (int i = 0; i < 4; ++i) {
    uint32_t o = (uint32_t)(i * 8192 + tid * 16);
    uint32_t r = o >> 8;              // row (256B rows)
    uint32_t pc = (o >> 4) & 15u;     // physical 16B chunk
    uint32_t j = pc ^ (r & 15u);      // logical chunk
    xsrc[i] = (uint32_t)(row0 + (int)r) * NIN + j * 4u;  // float elems
    xdst[i] = o;
  }

#define XSTAGE(pbuf, k0)                                        \
  { char* xb_ = smem + (pbuf) * XS_TILE;                        \
    _Pragma("unroll") for (int i_ = 0; i_ < 4; ++i_)            \
      gload16(x + xsrc[i_] + (k0), xb_ + xdst[i_]); }

  f32x16 acc[2][2];
#pragma unroll
  for (int mt = 0; mt < 2; ++mt)
#pragma unroll
    for (int nt = 0; nt < 2; ++nt)
#pragma unroll
      for (int q = 0; q < 16; ++q) acc[mt][nt][q] = 0.f;

  // W1F fragment base for this wave: c = wn*2+nt, elem = (c*4096+kb*32+l31)*8
  const unsigned short* wf0 = w1f + ((size_t)(wn * 2 + 0) * 4096 + l31) * 8;
  const unsigned short* wf1 = w1f + ((size_t)(wn * 2 + 1) * 4096 + l31) * 8;

  // A-fragment row base (fp32 LDS, 256B rows)
  const uint32_t ar0 = (uint32_t)(wm * 64 + l31) * 256u;        // mt=0
  const uint32_t ar1 = (uint32_t)(wm * 64 + 32 + l31) * 256u;   // mt=1

  // prologue
  XSTAGE(0, 0);
  __syncthreads();

  for (int t = 0; t < 16; ++t) {
    const int pc = t & 1;
    const char* xb = smem + pc * XS_TILE;

    // B fragments for this step: 8 coalesced 16B loads from L2 (issued first)
    bf16x8 bfr[2][4];
#pragma unroll
    for (int kk = 0; kk < 4; ++kk) {
      uint32_t kb = (uint32_t)(t * 8 + kk * 2 + lh);
      bfr[0][kk] = *(const bf16x8*)(wf0 + kb * 256u);
      bfr[1][kk] = *(const bf16x8*)(wf1 + kb * 256u);
    }

    // next x tile DMA (after B loads in program order: in-order vmcnt retire
    // keeps MFMA's B-wait from draining the HBM DMA)
    if (t < 15) XSTAGE(pc ^ 1, (t + 1) * BK);

#pragma unroll
    for (int kk = 0; kk < 4; ++kk) {
      // A fragments: fp32 from swizzled LDS + cvt to bf16
      bf16x8 a0, a1;
      {
        uint32_t j0 = (uint32_t)(kk * 4 + lh * 2);
        fx4 va = *(const fx4*)(xb + ar0 + ((j0 ^ (uint32_t)l15) << 4));
        fx4 vb = *(const fx4*)(xb + ar0 + (((j0 + 1) ^ (uint32_t)l15) << 4));
        FragU f;
        f.u[0] = cvtpk(va.x, va.y); f.u[1] = cvtpk(va.z, va.w);
        f.u[2] = cvtpk(vb.x, vb.y); f.u[3] = cvtpk(vb.z, vb.w);
        a0 = f.v;
        fx4 vc = *(const fx4*)(xb + ar1 + ((j0 ^ (uint32_t)l15) << 4));
        fx4 vd = *(const fx4*)(xb + ar1 + (((j0 + 1) ^ (uint32_t)l15) << 4));
        FragU g;
        g.u[0] = cvtpk(vc.x, vc.y); g.u[1] = cvtpk(vc.z, vc.w);
        g.u[2] = cvtpk(vd.x, vd.y); g.u[3] = cvtpk(vd.z, vd.w);
        a1 = g.v;
      }
      __builtin_amdgcn_s_setprio(1);
      acc[0][0] = __builtin_amdgcn_mfma_f32_32x32x16_bf16(a0, bfr[0][kk], acc[0][0], 0, 0, 0);
      acc[0][1] = __builtin_amdgcn_mfma_f32_32x32x16_bf16(a0, bfr[1][kk], acc[0][1], 0, 0, 0);
      acc[1][0] = __builtin_amdgcn_mfma_f32_32x32x16_bf16(a1, bfr[0][kk], acc[1][0], 0, 0, 0);
      acc[1][1] = __builtin_amdgcn_mfma_f32_32x32x16_bf16(a1, bfr[1][kk], acc[1][1], 0, 0, 0);
      __builtin_amdgcn_s_setprio(0);
    }
    __syncthreads();   // drains DMA (issued one compute-phase ago) + ds reads
  }

  // ---- layer-1 epilogue: bias+relu -> h bf16 [128][256] (32-chunk XOR) ----
  float b1v[2];
#pragma unroll
  for (int nt = 0; nt < 2; ++nt) b1v[nt] = b1[wn * 64 + nt * 32 + l31];

#pragma unroll
  for (int mt = 0; mt < 2; ++mt) {
#pragma unroll
    for (int nt = 0; nt < 2; ++nt) {
      int col = wn * 64 + nt * 32 + l31;
#pragma unroll
      for (int rg = 0; rg < 16; ++rg) {
        int row = wm * 64 + mt * 32 + (rg & 3) + 8 * (rg >> 2) + 4 * lh;
        float v = acc[mt][nt][rg] + b1v[nt];
        v = v > 0.f ? v : 0.f;
        int j = (col >> 3) ^ (row & 31);
        *(unsigned short*)(smem + row * 512 + (j << 4) + (col & 7) * 2) =
            (unsigned short)cvtpk(v, v);
      }
    }
  }
  __syncthreads();

  // ---- layer 2: y = relu(h @ W2^T + b2) ----
  f32x16 acc2;
#pragma unroll
  for (int q = 0; q < 16; ++q) acc2[q] = 0.f;

  const int r2 = (w >> 1) * 32;
  const int c2 = (w & 1) * 32;
  const int arow = r2 + l31;
  const uint32_t arx = (uint32_t)(arow & 31);
  const unsigned short* w2row = w2b + (size_t)(c2 + l31) * NMID + lh * 8;

#pragma unroll
  for (int kk = 0; kk < 16; ++kk) {
    bf16x8 a2 = *(const bf16x8*)(smem + arow * 512 +
                                 ((((uint32_t)(kk * 2 + lh)) ^ arx) << 4));
    bf16x8 bw = *(const bf16x8*)(w2row + kk * 16);
    acc2 = __builtin_amdgcn_mfma_f32_32x32x16_bf16(a2, bw, acc2, 0, 0, 0);
  }

  float bias2 = b2[c2 + l31];
#pragma unroll
  for (int rg = 0; rg < 16; ++rg) {
    int row = r2 + (rg & 3) + 8 * (rg >> 2) + 4 * lh;
    float v = acc2[rg] + bias2;
    v = v > 0.f ? v : 0.f;
    y[(size_t)(row0 + row) * NOUT + c2 + l31] = v;
  }
}

extern "C" void kernel_launch(void* const* d_in, const int* in_sizes, int n_in,
                              void* d_out, int out_size, void* d_ws, size_t ws_size,
                              hipStream_t stream) {
  const float* x  = (const float*)d_in[0];
  const float* W1 = (const float*)d_in[1];
  const float* b1 = (const float*)d_in[2];
  const float* W2 = (const float*)d_in[3];
  const float* b2 = (const float*)d_in[4];
  float* y = (float*)d_out;

  unsigned short* w1f = (unsigned short*)d_ws;            // 512 KB frag-layout
  unsigned short* w2b = w1f + (size_t)NMID * NIN;         // 32 KB rowmajor

  const int batch = in_sizes[0] / NIN;

  // 32768 W1-chunk threads + 4096 W2 threads = 36864 -> 144 blocks
  hipLaunchKernelGGL(cvt_weights, dim3(144), dim3(256), 0, stream,
                     W1, W2, w1f, w2b);

  static int lds_set = 0;
  if (!lds_set) {
    hipFuncSetAttribute((const void*)livenet_main,
                        hipFuncAttributeMaxDynamicSharedMemorySize, LDS_SZ);
    lds_set = 1;
  }
  hipLaunchKernelGGL(livenet_main, dim3(batch / BM), dim3(512), LDS_SZ, stream,
                     x, w1f, b1, w2b, b2, y);
}